// Round 1
// baseline (3955.527 us; speedup 1.0000x reference)
//
#include <hip/hip_runtime.h>
#include <math.h>

#define NNODES 100000
#define NEDGES 500000
#define FEAT 128
#define TDIM 128
#define QD 256      // FEAT + TDIM
#define KVD 384     // FEAT + FEAT + TDIM
#define KN 20
#define NB 1024
#define NH 4
#define HD 64       // QD / NH
#define KSTR 257    // padded k row stride (floats) to break bank conflicts

struct Params {
  const int*   src_idx;
  const float* cut_time;
  const float* node_features;
  const float* edge_features;
  const float* time_freq;
  const float* time_phase;
  const float* Wq; const float* Wk; const float* Wv; const float* Wo;
  const float* bo; const float* ln_g; const float* ln_b;
  const float* mw1; const float* mb1; const float* mw2; const float* mb2;
  float* emb1;   // workspace: [NB + NB*KN, FEAT] layer-1 embeddings
  float* out;    // [NB, FEAT]
};

// LAYER = 0: layer-1 eval over 21504 (node,time) pairs -> emb1
// LAYER = 1: layer-2 eval over 1024 sources -> out
template<int LAYER>
__global__ __launch_bounds__(256) void tgan_layer(Params p)
{
  __shared__ __align__(16) float kv[KN * KVD];   // 30720 B
  __shared__ __align__(16) float kbuf[KN * KSTR];// 20560 B (reused as obuf)
  __shared__ float qin[QD];
  __shared__ float qv[QD];
  __shared__ float scores[NH * KN];
  __shared__ float pbuf[NH * KN];
  __shared__ float xbuf[KVD];                    // [local(256) | node_feat(128)]
  __shared__ float h1[FEAT];
  __shared__ float red[8];
  __shared__ int   s_ngh[KN];
  __shared__ int   s_eidx[KN];
  __shared__ float s_delta[KN];

  const int b = blockIdx.x;
  const int j = threadIdx.x;

  // ---- derive (node, t) for this block ----
  int node; float t;
  if (LAYER == 0) {
    if (b < NB) {
      node = p.src_idx[b]; t = p.cut_time[b];
    } else {
      int i = (b - NB) / KN, k = (b - NB) % KN;
      unsigned h = (unsigned)p.src_idx[i] * 2654435761u + (unsigned)(k + 1) * 40503u;
      int ng = (int)(h % (unsigned)NNODES);
      if (((h >> 7) & 3u) == 0u) ng = 0;
      node = ng;
      t = p.cut_time[i] * ((float)((h >> 3) & 1023u) * (1.0f / 1024.0f));
    }
  } else {
    node = p.src_idx[b]; t = p.cut_time[b];
  }

  // ---- sample this node's neighbors (exact uint32 hash replica) ----
  if (j < KN) {
    unsigned h = (unsigned)node * 2654435761u + (unsigned)(j + 1) * 40503u;
    int ng = (int)(h % (unsigned)NNODES);
    if (((h >> 7) & 3u) == 0u) ng = 0;
    s_ngh[j]  = ng;
    s_eidx[j] = (int)((h * 97u + 13u) % (unsigned)NEDGES);
    float frac = (float)((h >> 3) & 1023u) * (1.0f / 1024.0f);
    s_delta[j] = t - t * frac;
  }

  // ---- q_in = [src_feat | cos(phase)] ----
  if (j < FEAT) {
    qin[j] = (LAYER == 0) ? p.node_features[(size_t)node * FEAT + j]
                          : p.emb1[(size_t)b * FEAT + j];
  } else {
    qin[j] = cosf(p.time_phase[j - FEAT]);
  }
  __syncthreads();

  // ---- build kv [KN][KVD] = [ngh_feat | edge_feat | cos(dt*freq+phase)] ----
  for (int idx = j; idx < KN * KVD; idx += 256) {
    int kk = idx / KVD, d = idx - kk * KVD;
    float v;
    if (d < FEAT) {
      v = (LAYER == 0) ? p.node_features[(size_t)s_ngh[kk] * FEAT + d]
                       : p.emb1[(size_t)(NB + b * KN + kk) * FEAT + d];
    } else if (d < 2 * FEAT) {
      v = p.edge_features[(size_t)s_eidx[kk] * FEAT + (d - FEAT)];
    } else {
      int dt = d - 2 * FEAT;
      v = cosf(s_delta[kk] * p.time_freq[dt] + p.time_phase[dt]);
    }
    kv[idx] = v;
  }
  __syncthreads();

  // ---- q = qin @ Wq[LAYER]  (thread j -> column j) ----
  {
    const float* W = p.Wq + LAYER * QD * QD;
    float acc = 0.f;
    for (int d = 0; d < QD; ++d) acc += qin[d] * W[d * QD + j];
    qv[j] = acc;
  }

  // ---- k, v = kv @ Wk, kv @ Wv  (thread j owns column j, all 20 rows) ----
  float kacc[KN], vacc[KN];
  #pragma unroll
  for (int kk = 0; kk < KN; ++kk) { kacc[kk] = 0.f; vacc[kk] = 0.f; }
  {
    const float* WkL = p.Wk + LAYER * KVD * QD;
    const float* WvL = p.Wv + LAYER * KVD * QD;
    for (int d = 0; d < KVD; d += 4) {
      float wk0 = WkL[(d + 0) * QD + j], wk1 = WkL[(d + 1) * QD + j];
      float wk2 = WkL[(d + 2) * QD + j], wk3 = WkL[(d + 3) * QD + j];
      float wv0 = WvL[(d + 0) * QD + j], wv1 = WvL[(d + 1) * QD + j];
      float wv2 = WvL[(d + 2) * QD + j], wv3 = WvL[(d + 3) * QD + j];
      #pragma unroll
      for (int kk = 0; kk < KN; ++kk) {
        float4 x = *(const float4*)&kv[kk * KVD + d];   // LDS broadcast
        kacc[kk] += x.x * wk0; kacc[kk] += x.y * wk1;
        kacc[kk] += x.z * wk2; kacc[kk] += x.w * wk3;
        vacc[kk] += x.x * wv0; vacc[kk] += x.y * wv1;
        vacc[kk] += x.z * wv2; vacc[kk] += x.w * wv3;
      }
    }
  }
  #pragma unroll
  for (int kk = 0; kk < KN; ++kk) kbuf[kk * KSTR + j] = kacc[kk];
  __syncthreads();

  // ---- attention scores: s[h][kk] = (q_h . k_h) * 0.125, masked ----
  if (j < NH * KN) {
    int kk = j % KN, h = j / KN;
    float acc = 0.f;
    for (int d = 0; d < HD; ++d) acc += qv[h * HD + d] * kbuf[kk * KSTR + h * HD + d];
    float s = acc * 0.125f;
    if (s_ngh[kk] == 0) s = -1e10f;
    scores[h * KN + kk] = s;
  }
  __syncthreads();

  // ---- softmax over kk per head ----
  if (j < NH) {
    float m = -INFINITY;
    for (int kk = 0; kk < KN; ++kk) m = fmaxf(m, scores[j * KN + kk]);
    float sum = 0.f;
    for (int kk = 0; kk < KN; ++kk) {
      float e = expf(scores[j * KN + kk] - m);
      pbuf[j * KN + kk] = e; sum += e;
    }
    float inv = 1.0f / sum;
    for (int kk = 0; kk < KN; ++kk) pbuf[j * KN + kk] *= inv;
  }
  __syncthreads();

  // ---- o[j] = sum_kk p[h][kk] * v[kk][j]  (v lives in this thread's regs) ----
  float o = 0.f;
  {
    int h = j / HD;
    #pragma unroll
    for (int kk = 0; kk < KN; ++kk) o += pbuf[h * KN + kk] * vacc[kk];
  }
  float* obuf = kbuf;  // reuse (all kbuf readers are past a barrier)
  obuf[j] = o;
  __syncthreads();

  // ---- out = o @ Wo + bo + q_in (residual), then LayerNorm ----
  float x;
  {
    const float* W = p.Wo + LAYER * QD * QD;
    float acc = 0.f;
    for (int d = 0; d < QD; ++d) acc += obuf[d] * W[d * QD + j];
    x = acc + p.bo[LAYER * QD + j] + qin[j];
  }
  {
    int lane = j & 63, wid = j >> 6;
    float s = x;
    #pragma unroll
    for (int off = 32; off > 0; off >>= 1) s += __shfl_down(s, off);
    if (lane == 0) red[wid] = s;
    __syncthreads();
    float mu = (red[0] + red[1] + red[2] + red[3]) * (1.0f / 256.0f);
    float dx = x - mu;
    float s2 = dx * dx;
    #pragma unroll
    for (int off = 32; off > 0; off >>= 1) s2 += __shfl_down(s2, off);
    if (lane == 0) red[4 + wid] = s2;
    __syncthreads();
    float var = (red[4] + red[5] + red[6] + red[7]) * (1.0f / 256.0f);
    float y = dx / sqrtf(var + 1e-5f) * p.ln_g[LAYER * QD + j] + p.ln_b[LAYER * QD + j];
    xbuf[j] = y;
  }
  if (j < FEAT) xbuf[QD + j] = p.node_features[(size_t)node * FEAT + j];
  __syncthreads();

  // ---- merge: out = mw2 @ relu(mw1 @ [local | node_feat] + mb1) + mb2 ----
  if (j < FEAT) {
    const float* m1 = p.mw1 + LAYER * KVD * FEAT;
    float a = p.mb1[LAYER * FEAT + j];
    for (int d = 0; d < KVD; ++d) a += xbuf[d] * m1[d * FEAT + j];
    h1[j] = fmaxf(a, 0.f);
  }
  __syncthreads();
  if (j < FEAT) {
    const float* m2 = p.mw2 + LAYER * FEAT * FEAT;
    float a = p.mb2[LAYER * FEAT + j];
    for (int d = 0; d < FEAT; ++d) a += h1[d] * m2[d * FEAT + j];
    float* dst = (LAYER == 0) ? (p.emb1 + (size_t)b * FEAT) : (p.out + (size_t)b * FEAT);
    dst[j] = a;
  }
}

extern "C" void kernel_launch(void* const* d_in, const int* in_sizes, int n_in,
                              void* d_out, int out_size, void* d_ws, size_t ws_size,
                              hipStream_t stream)
{
  Params p;
  p.src_idx       = (const int*)d_in[0];
  // d_in[1] target_idx_l, d_in[2] edge_idxs: unused by the reference output
  p.cut_time      = (const float*)d_in[3];
  p.node_features = (const float*)d_in[4];
  p.edge_features = (const float*)d_in[5];
  p.time_freq     = (const float*)d_in[6];
  p.time_phase    = (const float*)d_in[7];
  p.Wq  = (const float*)d_in[8];
  p.Wk  = (const float*)d_in[9];
  p.Wv  = (const float*)d_in[10];
  p.Wo  = (const float*)d_in[11];
  p.bo  = (const float*)d_in[12];
  p.ln_g = (const float*)d_in[13];
  p.ln_b = (const float*)d_in[14];
  p.mw1 = (const float*)d_in[15];
  p.mb1 = (const float*)d_in[16];
  p.mw2 = (const float*)d_in[17];
  p.mb2 = (const float*)d_in[18];
  p.emb1 = (float*)d_ws;                 // needs 21504*128*4 = 11,010,048 B
  p.out  = (float*)d_out;

  hipLaunchKernelGGL((tgan_layer<0>), dim3(NB + NB * KN), dim3(256), 0, stream, p);
  hipLaunchKernelGGL((tgan_layer<1>), dim3(NB), dim3(256), 0, stream, p);
}

// Round 5
// 1075.915 us; speedup vs baseline: 3.6764x; 3.6764x over previous
//
#include <hip/hip_runtime.h>
#include <math.h>

#define NNODES 100000
#define NEDGES 500000
#define FEAT 128
#define QD 256      // FEAT + TDIM
#define KVD 384     // FEAT + FEAT + TDIM
#define KN 20
#define NB 1024
#define G 4         // nodes per block
#define ROWS (G*KN) // 80  (= 5 exact M-tiles)
#define NT_Q 16     // QD/16
#define NT_F 8      // FEAT/16

// prepped-weight fragment offsets (bf16 elements), per layer
#define WOFF_Q  0
#define WOFF_K  65536
#define WOFF_V  163840
#define WOFF_O  262144
#define WOFF_M1 327680
#define WOFF_M2 376832
#define WLAYER  393216
#define EMB1_BYTES (21504u * 128u * 4u)   // 11,010,048

typedef __attribute__((ext_vector_type(8))) short bf16x8;
typedef __attribute__((ext_vector_type(4))) float f32x4;

__device__ __forceinline__ unsigned short f2bf(float f) {
  union { float f; unsigned u; } v; v.f = f;
  unsigned r = v.u + 0x7fffu + ((v.u >> 16) & 1u);
  return (unsigned short)(r >> 16);
}
__device__ __forceinline__ float bf2f(unsigned short u) {
  union { unsigned u; float f; } v; v.u = ((unsigned)u) << 16; return v.f;
}
__device__ __forceinline__ f32x4 zero4() {
  f32x4 z; z[0] = 0.f; z[1] = 0.f; z[2] = 0.f; z[3] = 0.f; return z;
}

// ---------------- weight prep: fp32 [K][N] -> bf16 B-fragment order ----------------
struct PrepP {
  const float *Wq, *Wk, *Wv, *Wo, *mw1, *mw2;
  unsigned short* dst;
};
__global__ __launch_bounds__(256) void prep_weights(PrepP p) {
  int idx = blockIdx.x * 256 + threadIdx.x;   // 786432 total
  if (idx >= 2 * WLAYER) return;
  int L = idx / WLAYER;
  int o = idx - L * WLAYER;
  const float* src; int base, Nn, lnt;
  if (o < 65536)       { src = p.Wq  + L * 65536; base = WOFF_Q;  Nn = 256; lnt = 4; }
  else if (o < 163840) { src = p.Wk  + L * 98304; base = WOFF_K;  Nn = 256; lnt = 4; }
  else if (o < 262144) { src = p.Wv  + L * 98304; base = WOFF_V;  Nn = 256; lnt = 4; }
  else if (o < 327680) { src = p.Wo  + L * 65536; base = WOFF_O;  Nn = 256; lnt = 4; }
  else if (o < 376832) { src = p.mw1 + L * 49152; base = WOFF_M1; Nn = 128; lnt = 3; }
  else                 { src = p.mw2 + L * 16384; base = WOFF_M2; Nn = 128; lnt = 3; }
  int oo = o - base;
  int r  = oo & 7;
  int l  = (oo >> 3) & 63;
  int t  = (oo >> 9) & ((1 << lnt) - 1);
  int kb = oo >> (9 + lnt);
  int k  = kb * 32 + ((l >> 4) << 3) + r;
  int n  = (t << 4) + (l & 15);
  p.dst[L * WLAYER + o] = f2bf(src[k * Nn + n]);
}

// ---------------- main fused kernel ----------------
struct Params {
  const int*   src_idx;
  const float* cut_time;
  const float* node_features;
  const float* edge_features;
  const float* time_freq;
  const float* time_phase;
  const float* bo; const float* ln_g; const float* ln_b;
  const float* mb1; const float* mb2;
  const unsigned short* wf;   // prepped bf16 fragments
  float* emb1;                // [21504][128] layer-1 embeddings (ws)
  float* out;                 // [1024][128]
};

template<int LAYER>
__global__ __launch_bounds__(512, 2) void tgan_layer(Params p)
{
  // U: staged KV panel (bf16 [80][128] swizzled, 20.5KB) then reused as
  // Kout bf16 [80][256] @0 and Vout @40960 (row stride 512B, XOR-swizzled)
  __shared__ __align__(16) unsigned char U[81920];
  __shared__ __align__(16) float qin[G][QD];
  __shared__ __align__(16) float qv[G][QD];
  __shared__ __align__(16) float obuf[G][QD];
  __shared__ __align__(16) float xbuf[G][KVD];
  __shared__ __align__(16) float h1b[G][FEAT];
  __shared__ float sc[G][4][KN];
  __shared__ int   s_node[G];
  __shared__ float s_tt[G];
  __shared__ int   s_ngh[ROWS];
  __shared__ int   s_eidx[ROWS];
  __shared__ float s_delta[ROWS];

  const int b   = blockIdx.x;
  const int tid = threadIdx.x;
  const int w   = tid >> 6;   // wave 0..7
  const int l   = tid & 63;

  const unsigned short* wfL = p.wf + LAYER * WLAYER;

  // ---- per-node meta ----
  if (tid < G) {
    int e = b * G + tid;
    int node; float t;
    if (LAYER == 0) {
      if (e < NB) { node = p.src_idx[e]; t = p.cut_time[e]; }
      else {
        int i = (e - NB) / KN, k = (e - NB) % KN;
        unsigned h = (unsigned)p.src_idx[i] * 2654435761u + (unsigned)(k + 1) * 40503u;
        int ng = (int)(h % (unsigned)NNODES);
        if (((h >> 7) & 3u) == 0u) ng = 0;
        node = ng;
        t = p.cut_time[i] * ((float)((h >> 3) & 1023u) * (1.0f / 1024.0f));
      }
    } else { node = p.src_idx[b * G + tid]; t = p.cut_time[b * G + tid]; }
    s_node[tid] = node; s_tt[tid] = t;
  }
  __syncthreads();
  if (tid < ROWS) {
    int g = tid / KN, k = tid - g * KN;
    unsigned h = (unsigned)s_node[g] * 2654435761u + (unsigned)(k + 1) * 40503u;
    int ng = (int)(h % (unsigned)NNODES);
    if (((h >> 7) & 3u) == 0u) ng = 0;
    s_ngh[tid]  = ng;
    s_eidx[tid] = (int)((h * 97u + 13u) % (unsigned)NEDGES);
    float frac = (float)((h >> 3) & 1023u) * (1.0f / 1024.0f);
    s_delta[tid] = s_tt[g] - s_tt[g] * frac;
  }
  // ---- qin = [src_feat | cos(phase)] ----
  for (int idx = tid; idx < G * QD; idx += 512) {
    int g = idx >> 8, d = idx & 255;
    float v;
    if (d < FEAT) v = (LAYER == 0) ? p.node_features[(size_t)s_node[g] * FEAT + d]
                                   : p.emb1[(size_t)(b * G + g) * FEAT + d];
    else          v = cosf(p.time_phase[d - FEAT]);
    qin[g][d] = v;
  }
  __syncthreads();

  // ---- q = qin @ Wq  (MFMA, M=4 of 16) ----
  {
    f32x4 aq[2]; aq[0] = zero4(); aq[1] = zero4();
    const unsigned short* wq = wfL + WOFF_Q;
    int row = l & 15, lk = (l >> 4) << 3;
    for (int kb = 0; kb < QD / 32; ++kb) {
      bf16x8 a;
      if (row < G) {
        const float* s = &qin[row][kb * 32 + lk];
        #pragma unroll
        for (int i = 0; i < 8; ++i) a[i] = (short)f2bf(s[i]);
      } else {
        #pragma unroll
        for (int i = 0; i < 8; ++i) a[i] = 0;
      }
      #pragma unroll
      for (int nti = 0; nti < 2; ++nti) {
        int t = w * 2 + nti;
        bf16x8 bfr = *(const bf16x8*)(wq + (((kb * NT_Q + t) * 64 + l) << 3));
        aq[nti] = __builtin_amdgcn_mfma_f32_16x16x32_bf16(a, bfr, aq[nti], 0, 0, 0);
      }
    }
    if ((l >> 4) == 0) {
      #pragma unroll
      for (int nti = 0; nti < 2; ++nti) {
        int col = (w * 2 + nti) * 16 + (l & 15);
        #pragma unroll
        for (int q = 0; q < 4; ++q) qv[q][col] = aq[nti][q];
      }
    }
  }

  // ---- K,V = kv @ Wk, kv @ Wv  (MFMA over 3 staged panels of 128 cols) ----
  f32x4 accK[5][2], accV[5][2];
  #pragma unroll
  for (int mt = 0; mt < 5; ++mt) { accK[mt][0]=zero4(); accK[mt][1]=zero4();
                                   accV[mt][0]=zero4(); accV[mt][1]=zero4(); }
  const unsigned short* wk = wfL + WOFF_K;
  const unsigned short* wv = wfL + WOFF_V;

  for (int pc = 0; pc < 3; ++pc) {
    __syncthreads();  // previous panel fully consumed
    for (int idx = tid; idx < ROWS * 16; idx += 512) {
      int r = idx >> 4, ddv = idx & 15;
      float vals[8];
      if (pc == 0) {
        const float* src = (LAYER == 0)
            ? &p.node_features[(size_t)s_ngh[r] * FEAT + ddv * 8]
            : &p.emb1[(size_t)(NB + b * ROWS + r) * FEAT + ddv * 8];
        *(float4*)&vals[0] = *(const float4*)src;
        *(float4*)&vals[4] = *(const float4*)(src + 4);
      } else if (pc == 1) {
        const float* src = &p.edge_features[(size_t)s_eidx[r] * FEAT + ddv * 8];
        *(float4*)&vals[0] = *(const float4*)src;
        *(float4*)&vals[4] = *(const float4*)(src + 4);
      } else {
        float dl = s_delta[r];
        #pragma unroll
        for (int i = 0; i < 8; ++i) {
          int d = ddv * 8 + i;
          vals[i] = cosf(dl * p.time_freq[d] + p.time_phase[d]);
        }
      }
      bf16x8 pk;
      #pragma unroll
      for (int i = 0; i < 8; ++i) pk[i] = (short)f2bf(vals[i]);
      int addr = (r << 8) + (ddv << 4);
      addr ^= (r & 7) << 4;                       // T2 swizzle (write side)
      *(bf16x8*)(U + addr) = pk;
    }
    __syncthreads();
    int row_a = l & 15, lk16 = (l >> 4) << 4;
    for (int kbl = 0; kbl < 4; ++kbl) {
      bf16x8 afr[5];
      #pragma unroll
      for (int mt = 0; mt < 5; ++mt) {
        int row = mt * 16 + row_a;
        int addr = (row << 8) + kbl * 64 + lk16;
        addr ^= (row & 7) << 4;                   // T2 swizzle (read side)
        afr[mt] = *(const bf16x8*)(U + addr);
      }
      int kbg = pc * 4 + kbl;
      #pragma unroll
      for (int nti = 0; nti < 2; ++nti) {
        int t = w * 2 + nti;
        size_t boff = ((size_t)(kbg * NT_Q + t) * 64 + l) << 3;
        bf16x8 bk = *(const bf16x8*)(wk + boff);
        bf16x8 bv = *(const bf16x8*)(wv + boff);
        #pragma unroll
        for (int mt = 0; mt < 5; ++mt) {
          accK[mt][nti] = __builtin_amdgcn_mfma_f32_16x16x32_bf16(afr[mt], bk, accK[mt][nti], 0, 0, 0);
          accV[mt][nti] = __builtin_amdgcn_mfma_f32_16x16x32_bf16(afr[mt], bv, accV[mt][nti], 0, 0, 0);
        }
      }
    }
  }
  __syncthreads();
  // write K (U@0) and V (U@40960) as bf16, row stride 512B, swizzled
  {
    int rbase = (l >> 4) << 2;
    #pragma unroll
    for (int mt = 0; mt < 5; ++mt) {
      #pragma unroll
      for (int nti = 0; nti < 2; ++nti) {
        int col2 = ((((w * 2 + nti) << 4) + (l & 15)) << 1);
        #pragma unroll
        for (int q = 0; q < 4; ++q) {
          int row = mt * 16 + rbase + q;
          int ad = (row << 9) + col2; ad ^= (row & 7) << 4;
          *(unsigned short*)(U + ad)         = f2bf(accK[mt][nti][q]);
          *(unsigned short*)(U + 40960 + ad) = f2bf(accV[mt][nti][q]);
        }
      }
    }
  }
  __syncthreads();

  // ---- scores: s[g][h][kk] = (q . k) / 8, masked ----
  if (tid < ROWS * 4) {
    int row = tid >> 2, h = tid & 3;
    int g = row / KN;
    float acc = 0.f;
    #pragma unroll
    for (int dv = 0; dv < 8; ++dv) {
      int ad = (row << 9) + (((h << 6) + (dv << 3)) << 1);
      ad ^= (row & 7) << 4;
      bf16x8 kf = *(const bf16x8*)(U + ad);
      const float* qp = &qv[g][(h << 6) + (dv << 3)];
      #pragma unroll
      for (int i = 0; i < 8; ++i) acc += bf2f((unsigned short)kf[i]) * qp[i];
    }
    float s = acc * 0.125f;
    if (s_ngh[row] == 0) s = -1e10f;
    sc[g][h][row - g * KN] = s;
  }
  __syncthreads();
  // ---- softmax per (g,h) ----
  if (tid < G * 4) {
    int g = tid >> 2, h = tid & 3;
    float m = -INFINITY;
    for (int k = 0; k < KN; ++k) m = fmaxf(m, sc[g][h][k]);
    float sum = 0.f;
    for (int k = 0; k < KN; ++k) sum += expf(sc[g][h][k] - m);
    float inv = 1.0f / sum;
    for (int k = 0; k < KN; ++k) sc[g][h][k] = expf(sc[g][h][k] - m) * inv;
  }
  __syncthreads();
  // ---- PV: obuf[g][c] = sum_kk p * V ----
  for (int idx = tid; idx < G * QD; idx += 512) {
    int g = idx >> 8, c = idx & 255;
    int h = c >> 6;
    float acc = 0.f;
    #pragma unroll
    for (int k = 0; k < KN; ++k) {
      int row = g * KN + k;
      int ad = 40960 + (row << 9) + (c << 1); ad ^= (row & 7) << 4;
      acc += bf2f(*(const unsigned short*)(U + ad)) * sc[g][h][k];
    }
    obuf[g][c] = acc;
  }
  __syncthreads();

  // ---- x = obuf @ Wo + bo + qin (residual) ----
  {
    f32x4 ao[2]; ao[0] = zero4(); ao[1] = zero4();
    const unsigned short* wo = wfL + WOFF_O;
    int row = l & 15, lk = (l >> 4) << 3;
    for (int kb = 0; kb < QD / 32; ++kb) {
      bf16x8 a;
      if (row < G) {
        const float* s = &obuf[row][kb * 32 + lk];
        #pragma unroll
        for (int i = 0; i < 8; ++i) a[i] = (short)f2bf(s[i]);
      } else {
        #pragma unroll
        for (int i = 0; i < 8; ++i) a[i] = 0;
      }
      #pragma unroll
      for (int nti = 0; nti < 2; ++nti) {
        int t = w * 2 + nti;
        bf16x8 bfr = *(const bf16x8*)(wo + (((kb * NT_Q + t) * 64 + l) << 3));
        ao[nti] = __builtin_amdgcn_mfma_f32_16x16x32_bf16(a, bfr, ao[nti], 0, 0, 0);
      }
    }
    if ((l >> 4) == 0) {
      #pragma unroll
      for (int nti = 0; nti < 2; ++nti) {
        int col = (w * 2 + nti) * 16 + (l & 15);
        #pragma unroll
        for (int q = 0; q < 4; ++q)
          xbuf[q][col] = ao[nti][q] + p.bo[LAYER * QD + col] + qin[q][col];
      }
    }
  }
  __syncthreads();

  // ---- LayerNorm (waves 0-3: one node each) + node-feat fill (waves 4-7) ----
  if (w < G) {
    int g = w;
    float x0 = xbuf[g][l], x1 = xbuf[g][l + 64], x2 = xbuf[g][l + 128], x3 = xbuf[g][l + 192];
    float s = x0 + x1 + x2 + x3;
    #pragma unroll
    for (int off = 32; off > 0; off >>= 1) s += __shfl_down(s, off);
    float mu = __shfl(s, 0) * (1.0f / 256.0f);
    float d0 = x0 - mu, d1 = x1 - mu, d2 = x2 - mu, d3 = x3 - mu;
    float s2 = d0 * d0 + d1 * d1 + d2 * d2 + d3 * d3;
    #pragma unroll
    for (int off = 32; off > 0; off >>= 1) s2 += __shfl_down(s2, off);
    float var = __shfl(s2, 0) * (1.0f / 256.0f);
    float rs = rsqrtf(var + 1e-5f);
    const float* lg = p.ln_g + LAYER * QD;
    const float* lb = p.ln_b + LAYER * QD;
    xbuf[g][l]       = d0 * rs * lg[l]       + lb[l];
    xbuf[g][l + 64]  = d1 * rs * lg[l + 64]  + lb[l + 64];
    xbuf[g][l + 128] = d2 * rs * lg[l + 128] + lb[l + 128];
    xbuf[g][l + 192] = d3 * rs * lg[l + 192] + lb[l + 192];
  } else {
    int g = w - G;
    xbuf[g][QD + l]      = p.node_features[(size_t)s_node[g] * FEAT + l];
    xbuf[g][QD + 64 + l] = p.node_features[(size_t)s_node[g] * FEAT + 64 + l];
  }
  __syncthreads();

  // ---- h1 = relu(xbuf @ mw1 + mb1)  (N=128, wave w owns n-tile w) ----
  {
    f32x4 am = zero4();
    const unsigned short* m1 = wfL + WOFF_M1;
    int row = l & 15, lk = (l >> 4) << 3;
    for (int kb = 0; kb < KVD / 32; ++kb) {
      bf16x8 a;
      if (row < G) {
        const float* s = &xbuf[row][kb * 32 + lk];
        #pragma unroll
        for (int i = 0; i < 8; ++i) a[i] = (short)f2bf(s[i]);
      } else {
        #pragma unroll
        for (int i = 0; i < 8; ++i) a[i] = 0;
      }
      bf16x8 bfr = *(const bf16x8*)(m1 + (((kb * NT_F + w) * 64 + l) << 3));
      am = __builtin_amdgcn_mfma_f32_16x16x32_bf16(a, bfr, am, 0, 0, 0);
    }
    if ((l >> 4) == 0) {
      int col = w * 16 + (l & 15);
      #pragma unroll
      for (int q = 0; q < 4; ++q)
        h1b[q][col] = fmaxf(am[q] + p.mb1[LAYER * FEAT + col], 0.f);
    }
  }
  __syncthreads();

  // ---- out = h1 @ mw2 + mb2 ----
  {
    f32x4 a2 = zero4();
    const unsigned short* m2 = wfL + WOFF_M2;
    int row = l & 15, lk = (l >> 4) << 3;
    for (int kb = 0; kb < FEAT / 32; ++kb) {
      bf16x8 a;
      if (row < G) {
        const float* s = &h1b[row][kb * 32 + lk];
        #pragma unroll
        for (int i = 0; i < 8; ++i) a[i] = (short)f2bf(s[i]);
      } else {
        #pragma unroll
        for (int i = 0; i < 8; ++i) a[i] = 0;
      }
      bf16x8 bfr = *(const bf16x8*)(m2 + (((kb * NT_F + w) * 64 + l) << 3));
      a2 = __builtin_amdgcn_mfma_f32_16x16x32_bf16(a, bfr, a2, 0, 0, 0);
    }
    if ((l >> 4) == 0) {
      int col = w * 16 + (l & 15);
      #pragma unroll
      for (int q = 0; q < 4; ++q) {
        float val = a2[q] + p.mb2[LAYER * FEAT + col];
        int e = b * G + q;
        if (LAYER == 0) p.emb1[(size_t)e * FEAT + col] = val;
        else            p.out[(size_t)e * FEAT + col]  = val;
      }
    }
  }
}

extern "C" void kernel_launch(void* const* d_in, const int* in_sizes, int n_in,
                              void* d_out, int out_size, void* d_ws, size_t ws_size,
                              hipStream_t stream)
{
  PrepP pp;
  pp.Wq  = (const float*)d_in[8];
  pp.Wk  = (const float*)d_in[9];
  pp.Wv  = (const float*)d_in[10];
  pp.Wo  = (const float*)d_in[11];
  pp.mw1 = (const float*)d_in[15];
  pp.mw2 = (const float*)d_in[17];
  pp.dst = (unsigned short*)((char*)d_ws + EMB1_BYTES);

  Params p;
  p.src_idx       = (const int*)d_in[0];
  p.cut_time      = (const float*)d_in[3];
  p.node_features = (const float*)d_in[4];
  p.edge_features = (const float*)d_in[5];
  p.time_freq     = (const float*)d_in[6];
  p.time_phase    = (const float*)d_in[7];
  p.bo   = (const float*)d_in[12];
  p.ln_g = (const float*)d_in[13];
  p.ln_b = (const float*)d_in[14];
  p.mb1  = (const float*)d_in[16];
  p.mb2  = (const float*)d_in[18];
  p.wf   = pp.dst;
  p.emb1 = (float*)d_ws;
  p.out  = (float*)d_out;

  hipLaunchKernelGGL(prep_weights, dim3(3072), dim3(256), 0, stream, pp);
  hipLaunchKernelGGL((tgan_layer<0>), dim3(21504 / G), dim3(512), 0, stream, p);
  hipLaunchKernelGGL((tgan_layer<1>), dim3(NB / G), dim3(512), 0, stream, p);
}